// Round 19
// baseline (722.192 us; speedup 1.0000x reference)
//
#include <hip/hip_runtime.h>

#define NPART_MAX 2048

typedef __attribute__((ext_vector_type(8))) short short8;
typedef __attribute__((ext_vector_type(4))) float f32x4;

__device__ __forceinline__ float bf2f(uint u) {
    union { uint u; float f; } v; v.u = u << 16; return v.f;
}
__device__ __forceinline__ ushort f2bf(float f) {
    union { float f; uint u; } v; v.f = f;
    uint r = v.u + 0x7fffu + ((v.u >> 16) & 1u);
    return (ushort)(r >> 16);
}

// ---------------- phase 0: counting sort by dst (both etypes per launch) ----------------
__global__ __launch_bounds__(256) void hist2(const int* __restrict__ dw, const int* __restrict__ dl,
                                             int E, int* __restrict__ cw, int* __restrict__ cl) {
    const int half = gridDim.x >> 1;
    const bool second = (int)blockIdx.x >= half;
    const int* dst = second ? dl : dw;
    int* cnt = second ? cl : cw;
    const int b = second ? blockIdx.x - half : blockIdx.x;
    for (int e = b * 256 + threadIdx.x; e < E; e += half * 256)
        atomicAdd(&cnt[dst[e]], 1);
}

__global__ __launch_bounds__(256) void scan2(const int* __restrict__ cw, const int* __restrict__ cl,
                                             int n, int* offw, int* curw, int* offl, int* curl) {
    const int* cnt = blockIdx.x ? cl : cw;
    int* off = blockIdx.x ? offl : offw;
    int* cur = blockIdx.x ? curl : curw;
    __shared__ int warpsums[4];
    __shared__ int s_carry;
    if (threadIdx.x == 0) s_carry = 0;
    __syncthreads();
    for (int base = 0; base < n; base += 1024) {
        int i0 = base + threadIdx.x * 4;
        int v0 = (i0 + 0 < n) ? cnt[i0 + 0] : 0;
        int v1 = (i0 + 1 < n) ? cnt[i0 + 1] : 0;
        int v2 = (i0 + 2 < n) ? cnt[i0 + 2] : 0;
        int v3 = (i0 + 3 < n) ? cnt[i0 + 3] : 0;
        int tsum = v0 + v1 + v2 + v3;
        int lane = threadIdx.x & 63, w = threadIdx.x >> 6;
        int x = tsum;
        for (int d = 1; d < 64; d <<= 1) {
            int y = __shfl_up(x, d);
            if (lane >= d) x += y;
        }
        if (lane == 63) warpsums[w] = x;
        __syncthreads();
        int woff = 0;
        for (int k = 0; k < w; ++k) woff += warpsums[k];
        int excl = x - tsum + woff + s_carry;
        if (i0 + 0 < n) { off[i0 + 0] = excl; cur[i0 + 0] = excl; } excl += v0;
        if (i0 + 1 < n) { off[i0 + 1] = excl; cur[i0 + 1] = excl; } excl += v1;
        if (i0 + 2 < n) { off[i0 + 2] = excl; cur[i0 + 2] = excl; } excl += v2;
        if (i0 + 3 < n) { off[i0 + 3] = excl; cur[i0 + 3] = excl; } excl += v3;
        __syncthreads();
        if (threadIdx.x == 255) s_carry = excl;
        __syncthreads();
    }
    if (threadIdx.x == 0) off[n] = s_carry;
}

__global__ __launch_bounds__(256) void scatter2(
    const int* __restrict__ sw, const int* __restrict__ dw,
    const int* __restrict__ sl, const int* __restrict__ dl, int E,
    int* __restrict__ curw, int* __restrict__ curl,
    int* __restrict__ permw, int* __restrict__ ssrcw, int* __restrict__ sdstw,
    int* __restrict__ perml, int* __restrict__ ssrcl, int* __restrict__ sdstl) {
    const int half = gridDim.x >> 1;
    const bool second = (int)blockIdx.x >= half;
    const int* src = second ? sl : sw;
    const int* dst = second ? dl : dw;
    int* cursor = second ? curl : curw;
    int* perm = second ? perml : permw;
    int* ssrc = second ? ssrcl : ssrcw;
    int* sdst = second ? sdstl : sdstw;
    const int b = second ? blockIdx.x - half : blockIdx.x;
    for (int e = b * 256 + threadIdx.x; e < E; e += half * 256) {
        int d = dst[e];
        int p = atomicAdd(&cursor[d], 1);
        perm[p] = e;
        ssrc[p] = src[e];
        sdst[p] = d;
    }
}

// ---------------- dual linear fp32 col-stats ----------------
__device__ __forceinline__ void statsf_body(
    int b, int nb, const float4* __restrict__ x4, int M,
    float* __restrict__ psum, float* __restrict__ psq) {
    const int cg = threadIdx.x & 31;
    const int sub = threadIdx.x >> 5;
    float s0=0,s1=0,s2=0,s3=0,q0=0,q1=0,q2=0,q3=0;
    for (int r = b * 8 + sub; r < M; r += nb * 8) {
        float4 v = x4[(size_t)r * 32 + cg];
        s0 += v.x; q0 += v.x * v.x;
        s1 += v.y; q1 += v.y * v.y;
        s2 += v.z; q2 += v.z * v.z;
        s3 += v.w; q3 += v.w * v.w;
    }
    __shared__ float rs[256][4], rq[256][4];
    rs[threadIdx.x][0]=s0; rs[threadIdx.x][1]=s1; rs[threadIdx.x][2]=s2; rs[threadIdx.x][3]=s3;
    rq[threadIdx.x][0]=q0; rq[threadIdx.x][1]=q1; rq[threadIdx.x][2]=q2; rq[threadIdx.x][3]=q3;
    __syncthreads();
    if (sub == 0) {
        #pragma unroll
        for (int k = 1; k < 8; ++k) {
            s0 += rs[k*32+cg][0]; s1 += rs[k*32+cg][1];
            s2 += rs[k*32+cg][2]; s3 += rs[k*32+cg][3];
            q0 += rq[k*32+cg][0]; q1 += rq[k*32+cg][1];
            q2 += rq[k*32+cg][2]; q3 += rq[k*32+cg][3];
        }
        psum[b*128 + cg*4+0] = s0; psq[b*128 + cg*4+0] = q0;
        psum[b*128 + cg*4+1] = s1; psq[b*128 + cg*4+1] = q1;
        psum[b*128 + cg*4+2] = s2; psq[b*128 + cg*4+2] = q2;
        psum[b*128 + cg*4+3] = s3; psq[b*128 + cg*4+3] = q3;
    }
}

__global__ __launch_bounds__(256) void stats_f32_2(
    const float4* xa, float* psa, float* pqa,
    const float4* xb, float* psb, float* pqb, int M) {
    const int half = gridDim.x >> 1;
    const bool second = (int)blockIdx.x >= half;
    statsf_body(second ? blockIdx.x - half : blockIdx.x, half,
                second ? xb : xa, M, second ? psb : psa, second ? pqb : pqa);
}

// ---------------- dual gather stats: run-hoisted hv + batched hu prefetch ----------------
__global__ __launch_bounds__(256) void gather_stats2(
    const uint2* __restrict__ hu4, const uint2* __restrict__ hv4,
    const int* __restrict__ sw, const int* __restrict__ dw,
    float* __restrict__ psumW, float* __restrict__ psqW,
    const int* __restrict__ sl, const int* __restrict__ dl,
    float* __restrict__ psumL, float* __restrict__ psqL, int E) {
    const int gh = gridDim.x >> 1;
    const bool second = (int)blockIdx.x >= gh;
    const int* sidx = second ? sl : sw;
    const int* didx = second ? dl : dw;
    float* psum = second ? psumL : psumW;
    float* psq  = second ? psqL  : psqW;
    const int b = second ? blockIdx.x - gh : blockIdx.x;

    const int lane = threadIdx.x & 63;
    const int w = threadIdx.x >> 6;
    const int half = lane >> 5;
    const int cg = lane & 31;
    const int gwave = (b * 256 + threadIdx.x) >> 6;
    const int nwave = (gh * 256) >> 6;
    float s0=0,s1=0,s2=0,s3=0,q0=0,q1=0,q2=0,q3=0;
    for (int base = gwave * 64; base < E; base += nwave * 64) {
        int e = base + lane;
        int su = (e < E) ? sidx[e] : 0;
        int dv = (e < E) ? didx[e] : 0;
        int cnt = min(64, E - base);
        int curd = -1;
        float hv0=0,hv1=0,hv2=0,hv3=0;
        float rs0=0,rs1=0,rs2=0,rs3=0,rq0=0,rq1=0,rq2=0,rq3=0,rlen=0;
        auto flush = [&]() {
            if (curd >= 0) {
                s0 += rs0 + rlen*hv0; q0 += rq0 + 2.f*hv0*rs0 + rlen*hv0*hv0;
                s1 += rs1 + rlen*hv1; q1 += rq1 + 2.f*hv1*rs1 + rlen*hv1*hv1;
                s2 += rs2 + rlen*hv2; q2 += rq2 + 2.f*hv2*rs2 + rlen*hv2*hv2;
                s3 += rs3 + rlen*hv3; q3 += rq3 + 2.f*hv3*rs3 + rlen*hv3*hv3;
            }
        };
        auto acc_run = [&](int eidx, uint2 uu) {
            int dd = __shfl(dv, eidx);
            if (dd != curd) {
                flush();
                curd = dd;
                uint2 vv = hv4[(size_t)dd * 32 + cg];
                hv0 = bf2f(vv.x & 0xffffu); hv1 = bf2f(vv.x >> 16);
                hv2 = bf2f(vv.y & 0xffffu); hv3 = bf2f(vv.y >> 16);
                rs0=rs1=rs2=rs3=0; rq0=rq1=rq2=rq3=0; rlen=0;
            }
            float u0 = bf2f(uu.x & 0xffffu), u1 = bf2f(uu.x >> 16);
            float u2 = bf2f(uu.y & 0xffffu), u3 = bf2f(uu.y >> 16);
            rs0 += u0; rq0 += u0*u0;
            rs1 += u1; rq1 += u1*u1;
            rs2 += u2; rq2 += u2*u2;
            rs3 += u3; rq3 += u3*u3;
            rlen += 1.f;
        };
        if (cnt == 64) {
            #pragma unroll
            for (int bb = 0; bb < 4; ++bb) {
                uint2 pre[8];
                #pragma unroll
                for (int k = 0; k < 8; ++k) {
                    int a = __shfl(su, 2 * (bb * 8 + k) + half);
                    pre[k] = hu4[(size_t)a * 32 + cg];
                }
                #pragma unroll
                for (int k = 0; k < 8; ++k)
                    acc_run(2 * (bb * 8 + k) + half, pre[k]);
            }
        } else {
            for (int j = 0; j < 32; ++j) {
                int eidx = 2 * j + half;
                if (eidx < cnt) {
                    int a = __shfl(su, eidx);
                    acc_run(eidx, hu4[(size_t)a * 32 + cg]);
                }
            }
        }
        flush();
    }
    __shared__ float redS[8][32][4], redQ[8][32][4];
    const int ri = w * 2 + half;
    redS[ri][cg][0]=s0; redS[ri][cg][1]=s1; redS[ri][cg][2]=s2; redS[ri][cg][3]=s3;
    redQ[ri][cg][0]=q0; redQ[ri][cg][1]=q1; redQ[ri][cg][2]=q2; redQ[ri][cg][3]=q3;
    __syncthreads();
    if (threadIdx.x < 128) {
        int c = threadIdx.x;
        int cgg = c >> 2, k = c & 3;
        float s = 0.f, q = 0.f;
        #pragma unroll
        for (int i = 0; i < 8; ++i) { s += redS[i][cgg][k]; q += redQ[i][cgg][k]; }
        psum[(size_t)b * 128 + c] = s;
        psq [(size_t)b * 128 + c] = q;
    }
}

// ---------------- per-column reduce of partials -> scale/shift ----------------
__device__ __forceinline__ void reduce_body(
    int c, const float* __restrict__ psum, const float* __restrict__ psq,
    int nblk, int C, int M,
    const float* __restrict__ g1, const float* __restrict__ b1,
    float* __restrict__ scale1, float* __restrict__ shift1,
    const float* g2, const float* b2, float* scale2, float* shift2) {
    double s = 0.0, q = 0.0;
    for (int i = threadIdx.x; i < nblk; i += 256) {
        s += (double)psum[(size_t)i * C + c];
        q += (double)psq [(size_t)i * C + c];
    }
    __shared__ double ss[256], qs[256];
    ss[threadIdx.x] = s; qs[threadIdx.x] = q;
    __syncthreads();
    for (int d = 128; d > 0; d >>= 1) {
        if (threadIdx.x < d) {
            ss[threadIdx.x] += ss[threadIdx.x + d];
            qs[threadIdx.x] += qs[threadIdx.x + d];
        }
        __syncthreads();
    }
    if (threadIdx.x == 0) {
        double m = ss[0] / (double)M;
        double v = qs[0] / (double)M - m * m;
        if (v < 0.0) v = 0.0;
        double rs = 1.0 / sqrt(v + 1e-5);
        float mf = (float)m;
        float sc1 = (float)(rs * (double)g1[c]);
        scale1[c] = sc1;
        shift1[c] = b1[c] - mf * sc1;
        if (g2) {
            float sc2 = (float)(rs * (double)g2[c]);
            scale2[c] = sc2;
            shift2[c] = b2[c] - mf * sc2;
        }
    }
}

__global__ __launch_bounds__(256) void reduce_stats(
    const float* psum, const float* psq, int nblk, int C, int M,
    const float* g1, const float* b1, float* scale1, float* shift1,
    const float* g2, const float* b2, float* scale2, float* shift2) {
    reduce_body(blockIdx.x, psum, psq, nblk, C, M, g1, b1, scale1, shift1, g2, b2, scale2, shift2);
}

__global__ __launch_bounds__(256) void reduce_stats2(
    const float* psumA, const float* psqA, int nblkA, int CA, int MA,
    const float* gA, const float* bA, float* scaleA, float* shiftA,
    const float* psumB, const float* psqB, int nblkB, int CB, int MB,
    const float* gB, const float* bB, float* scaleB, float* shiftB) {
    if ((int)blockIdx.x < CA)
        reduce_body(blockIdx.x, psumA, psqA, nblkA, CA, MA, gA, bA, scaleA, shiftA,
                    nullptr, nullptr, nullptr, nullptr);
    else
        reduce_body(blockIdx.x - CA, psumB, psqB, nblkB, CB, MB, gB, bB, scaleB, shiftB,
                    nullptr, nullptr, nullptr, nullptr);
}

// ---------------- parallel BN fold + MFMA-fragment pack ----------------
__device__ __forceinline__ void fold_body(
    int b, const float* __restrict__ scale, const float* __restrict__ shift, int C,
    const float* __restrict__ W, const float* __restrict__ bias,
    ushort* __restrict__ Wp, float* __restrict__ beff) {
    const int KT = C / 32;
    __shared__ float slab[32 * 128];
    if (b < KT) {
        const int kt = b;
        for (int i = threadIdx.x; i < 32 * 128; i += 256) {
            int kr = i >> 7, d = i & 127;
            int c = kt * 32 + kr;
            slab[i] = W[(size_t)c * 128 + d] * scale[c];
        }
        __syncthreads();
        #pragma unroll
        for (int t0 = 0; t0 < 512; t0 += 256) {
            int t = t0 + threadIdx.x;
            int lane = t & 63, dt = t >> 6;
            int d = dt * 16 + (lane & 15);
            int kb = (lane >> 4) * 8;
            uint4 o;
            o.x = (uint)f2bf(slab[(kb+0)*128 + d]) | ((uint)f2bf(slab[(kb+1)*128 + d]) << 16);
            o.y = (uint)f2bf(slab[(kb+2)*128 + d]) | ((uint)f2bf(slab[(kb+3)*128 + d]) << 16);
            o.z = (uint)f2bf(slab[(kb+4)*128 + d]) | ((uint)f2bf(slab[(kb+5)*128 + d]) << 16);
            o.w = (uint)f2bf(slab[(kb+6)*128 + d]) | ((uint)f2bf(slab[(kb+7)*128 + d]) << 16);
            *(uint4*)(Wp + (size_t)((dt * KT + kt) * 64 + lane) * 8) = o;
        }
    } else {
        const int bb = b - KT;
        const int dl = threadIdx.x & 15, ci = threadIdx.x >> 4;
        const int d = bb * 16 + dl;
        float a = 0.f;
        for (int c = ci; c < C; c += 16)
            a += shift[c] * W[(size_t)c * 128 + d];
        float* red = slab;
        red[threadIdx.x] = a;
        __syncthreads();
        if (ci == 0) {
            #pragma unroll
            for (int k = 1; k < 16; ++k) a += red[k * 16 + dl];
            beff[d] = bias[d] + a;
        }
    }
}

__global__ __launch_bounds__(256) void pack_fold_par(
    const float* scale, const float* shift, int C,
    const float* W, const float* bias, ushort* Wp, float* beff) {
    fold_body(blockIdx.x, scale, shift, C, W, bias, Wp, beff);
}

__global__ __launch_bounds__(256) void pack_fold2(
    const float* scaleA, const float* shiftA, int CA, const float* WA, const float* biasA,
    ushort* WpA, float* beffA,
    const float* scaleB, const float* shiftB, int CB, const float* WB, const float* biasB,
    ushort* WpB, float* beffB) {
    const int nA = CA / 32 + 8;
    const bool second = (int)blockIdx.x >= nA;
    fold_body(second ? blockIdx.x - nA : blockIdx.x,
              second ? scaleB : scaleA, second ? shiftB : shiftA, second ? CB : CA,
              second ? WB : WA, second ? biasB : biasA,
              second ? WpB : WpA, second ? beffB : beffA);
}

// ---------------- plain MFMA GEMM. MODE: 0=bf16 bias+relu, 1=f32 bias+relu, 2=bf16 plain ----------------
template<int KT, int MODE>
__device__ __forceinline__ void gemm_body(
    int b, const ushort* __restrict__ X,
    const ushort* __restrict__ Wp, const float* __restrict__ beff,
    ushort* __restrict__ Yb, float* __restrict__ Yf, int M) {
    constexpr int K = KT * 32;
    const int lane = threadIdx.x & 63;
    const int w = threadIdx.x >> 6;
    const int r0 = b * 128 + w * 32;
    const int rlo = lane & 15, khi = lane >> 4;

    f32x4 acc[2][8];
    #pragma unroll
    for (int rt = 0; rt < 2; ++rt)
        #pragma unroll
        for (int dt = 0; dt < 8; ++dt)
            acc[rt][dt] = (f32x4){0.f, 0.f, 0.f, 0.f};

    int row[2], idx[2];
    bool ok[2];
    #pragma unroll
    for (int rt = 0; rt < 2; ++rt) {
        row[rt] = r0 + rt * 16 + rlo;
        ok[rt] = row[rt] < M;
        idx[rt] = ok[rt] ? row[rt] : 0;
    }

    for (int kt = 0; kt < KT; ++kt) {
        short8 wf[8];
        #pragma unroll
        for (int dt = 0; dt < 8; ++dt)
            wf[dt] = *(const short8*)(Wp + (size_t)((dt * KT + kt) * 64 + lane) * 8);
        #pragma unroll
        for (int rt = 0; rt < 2; ++rt) {
            short8 bv = *(const short8*)(X + (size_t)idx[rt] * K + kt * 32 + khi * 8);
            #pragma unroll
            for (int dt = 0; dt < 8; ++dt)
                acc[rt][dt] = __builtin_amdgcn_mfma_f32_16x16x32_bf16(wf[dt], bv, acc[rt][dt], 0, 0, 0);
        }
    }

    #pragma unroll
    for (int rt = 0; rt < 2; ++rt) {
        if (!ok[rt]) continue;
        #pragma unroll
        for (int dt = 0; dt < 8; ++dt) {
            float v0, v1, v2, v3;
            if constexpr (MODE == 2) {
                v0 = acc[rt][dt][0]; v1 = acc[rt][dt][1];
                v2 = acc[rt][dt][2]; v3 = acc[rt][dt][3];
            } else {
                const float4 bz = *(const float4*)(beff + dt * 16 + khi * 4);
                v0 = fmaxf(acc[rt][dt][0] + bz.x, 0.f);
                v1 = fmaxf(acc[rt][dt][1] + bz.y, 0.f);
                v2 = fmaxf(acc[rt][dt][2] + bz.z, 0.f);
                v3 = fmaxf(acc[rt][dt][3] + bz.w, 0.f);
            }
            if constexpr (MODE == 1) {
                *(float4*)(Yf + (size_t)row[rt] * 128 + dt * 16 + khi * 4) = make_float4(v0, v1, v2, v3);
            } else {
                uint2 pk;
                pk.x = (uint)f2bf(v0) | ((uint)f2bf(v1) << 16);
                pk.y = (uint)f2bf(v2) | ((uint)f2bf(v3) << 16);
                *(uint2*)(Yb + (size_t)row[rt] * 128 + dt * 16 + khi * 4) = pk;
            }
        }
    }
}

__global__ __launch_bounds__(256) void gemm_final(
    const ushort* X, const ushort* Wp, const float* beff, float* Yf, int M) {
    gemm_body<8, 1>(blockIdx.x, X, Wp, beff, nullptr, Yf, M);
}

__global__ __launch_bounds__(256) void gemm_dual(
    const ushort* X,
    const ushort* Wp1, const float* beff1, ushort* Y1,
    const ushort* Wp2, const float* beff2, ushort* Y2, int M) {
    const int half = gridDim.x >> 1;
    const bool second = (int)blockIdx.x >= half;
    gemm_body<4, 0>(second ? blockIdx.x - half : blockIdx.x, X,
                    second ? Wp2 : Wp1, second ? beff2 : beff1,
                    second ? Y2 : Y1, nullptr, M);
}

// 4 node GEMMs (no bias/relu): hu@Wp1->HUw, hv@Wp1->HVw, hu@Wp2->HUl, hv@Wp2->HVl
__global__ __launch_bounds__(256) void gemm_quad(
    const ushort* hu, const ushort* hv,
    const ushort* Wp1, const ushort* Wp2,
    ushort* HUw, ushort* HVw, ushort* HUl, ushort* HVl, int M) {
    const int gq = gridDim.x >> 2;
    const int q = blockIdx.x / gq;
    const int b = blockIdx.x - q * gq;
    const ushort* X = (q & 1) ? hv : hu;
    const ushort* Wp = (q >= 2) ? Wp2 : Wp1;
    ushort* Y = (q == 0) ? HUw : (q == 1) ? HVw : (q == 2) ? HUl : HVl;
    gemm_body<4, 2>(b, X, Wp, nullptr, Y, nullptr, M);
}

// ---------------- seg-GEMM: 64-row blocks, LDS-staged bf16 gather, fused segmented mean ----------------
// Stage: block cooperatively gathers 64 fp32 rows, converts to bf16 on the fly, stores into
// a 16.9KB LDS tile (8 independent float4 loads/thread -> high MLP, low VGPR, low LDS).
// MFMA reads short8 fragments directly from LDS; the same LDS is reused as the bf16
// output tile for the segmented-mean epilogue.
__device__ __forceinline__ void gemm_seg_body(
    int b, const float* __restrict__ XF, const int* __restrict__ perm,
    const int* __restrict__ sdst, const int* __restrict__ cnt,
    const ushort* __restrict__ Wp, const float* __restrict__ beff,
    float* __restrict__ hacc, int M) {
    __shared__ ushort xs[64 * 132];        // 16896 B; staging tile, reused as output tile
    __shared__ int   s_node[64];
    __shared__ float s_scale[64];
    __shared__ int   s_pidx[64];
    const int tid = threadIdx.x;
    const int lane = tid & 63;
    const int w = tid >> 6;
    const int rb = b * 64;
    const int rlo = lane & 15, khi = lane >> 4;

    if (tid < 64) {
        int r = rb + tid;
        bool in = (r < M);
        int nd = in ? sdst[r] : -1;
        s_node[tid] = nd;
        s_scale[tid] = (nd >= 0) ? 0.5f / fmaxf((float)cnt[nd], 1.f) : 0.f;
        s_pidx[tid] = in ? perm[r] : 0;
    }
    __syncthreads();

    // cooperative gather: 64 rows x 32 chunks of 4 floats = 2048 chunks; 8 per thread
    {
        float4 v[8];
        int rowi[8], coli[8];
        #pragma unroll
        for (int i = 0; i < 8; ++i) {
            int c = tid + 256 * i;
            rowi[i] = c >> 5;
            coli[i] = c & 31;
            v[i] = *(const float4*)(XF + (size_t)s_pidx[rowi[i]] * 128 + coli[i] * 4);
        }
        #pragma unroll
        for (int i = 0; i < 8; ++i) {
            uint2 o;
            o.x = (uint)f2bf(v[i].x) | ((uint)f2bf(v[i].y) << 16);
            o.y = (uint)f2bf(v[i].z) | ((uint)f2bf(v[i].w) << 16);
            *(uint2*)&xs[rowi[i] * 132 + coli[i] * 4] = o;
        }
    }
    __syncthreads();

    f32x4 acc[8];
    #pragma unroll
    for (int dt = 0; dt < 8; ++dt)
        acc[dt] = (f32x4){0.f, 0.f, 0.f, 0.f};

    const int row = rb + w * 16 + rlo;
    const bool ok = row < M;
    const int rl = w * 16 + rlo;

    #pragma unroll
    for (int kt = 0; kt < 4; ++kt) {
        short8 bv = *(const short8*)&xs[rl * 132 + kt * 32 + khi * 8];
        #pragma unroll
        for (int dt = 0; dt < 8; ++dt) {
            short8 wf = *(const short8*)(Wp + (size_t)((dt * 4 + kt) * 64 + lane) * 8);
            acc[dt] = __builtin_amdgcn_mfma_f32_16x16x32_bf16(wf, bv, acc[dt], 0, 0, 0);
        }
    }
    __syncthreads();   // all LDS reads of xs done before tile overwrite

    #pragma unroll
    for (int dt = 0; dt < 8; ++dt) {
        const float4 bz = *(const float4*)(beff + dt * 16 + khi * 4);
        float v0 = 0.f, v1 = 0.f, v2 = 0.f, v3 = 0.f;
        if (ok) {
            v0 = fmaxf(acc[dt][0] + bz.x, 0.f);
            v1 = fmaxf(acc[dt][1] + bz.y, 0.f);
            v2 = fmaxf(acc[dt][2] + bz.z, 0.f);
            v3 = fmaxf(acc[dt][3] + bz.w, 0.f);
        }
        uint2 pk;
        pk.x = (uint)f2bf(v0) | ((uint)f2bf(v1) << 16);
        pk.y = (uint)f2bf(v2) | ((uint)f2bf(v3) << 16);
        *(uint2*)&xs[rl * 132 + dt * 16 + khi * 4] = pk;
    }
    __syncthreads();

    // epilogue: 4 segments x 16 rows, uint col-pairs (64 per block)
    const int cp = tid & 63;
    const int rs = (tid >> 6) * 16;
    int cur = s_node[rs];
    float scl = s_scale[rs];
    float su0 = 0.f, su1 = 0.f;
    for (int r = rs; r < rs + 16; ++r) {
        int nd = s_node[r];
        if (nd != cur) {
            if (cur >= 0) {
                atomicAdd(&hacc[(size_t)cur * 128 + 2*cp],     su0 * scl);
                atomicAdd(&hacc[(size_t)cur * 128 + 2*cp + 1], su1 * scl);
            }
            cur = nd; scl = s_scale[r]; su0 = 0.f; su1 = 0.f;
        }
        uint u = *(const uint*)&xs[r * 132 + 2*cp];
        su0 += bf2f(u & 0xffffu);
        su1 += bf2f(u >> 16);
    }
    if (cur >= 0) {
        atomicAdd(&hacc[(size_t)cur * 128 + 2*cp],     su0 * scl);
        atomicAdd(&hacc[(size_t)cur * 128 + 2*cp + 1], su1 * scl);
    }
}

__global__ __launch_bounds__(256) void gemm_seg2(
    const float* XA, const int* permA, const int* sdstA, const int* cntA,
    const ushort* WpA, const float* beffA, int MA,
    const float* XB, const int* permB, const int* sdstB, const int* cntB,
    const ushort* WpB, const float* beffB, int MB,
    float* hacc) {
    const int half = gridDim.x >> 1;
    const bool second = (int)blockIdx.x >= half;
    gemm_seg_body(second ? blockIdx.x - half : blockIdx.x,
                  second ? XB : XA, second ? permB : permA,
                  second ? sdstB : sdstA, second ? cntB : cntA,
                  second ? WpB : WpA, second ? beffB : beffA,
                  hacc, second ? MB : MA);
}

// ---------------- edge gather-add-relu + segmented mean (dual, run-hoisted HV, batched HU prefetch) ----------------
__global__ __launch_bounds__(256) void edge_seg2(
    const uint* __restrict__ HUw, const uint* __restrict__ HVw,
    const int* __restrict__ sw, const int* __restrict__ dw,
    const int* __restrict__ cw, const float* __restrict__ bw,
    const uint* __restrict__ HUl, const uint* __restrict__ HVl,
    const int* __restrict__ sl, const int* __restrict__ dl,
    const int* __restrict__ cl, const float* __restrict__ bl,
    float* __restrict__ hacc, int E) {
    const int gh = gridDim.x >> 1;
    const bool second = (int)blockIdx.x >= gh;
    const uint* HU = second ? HUl : HUw;
    const uint* HV = second ? HVl : HVw;
    const int* sidx = second ? sl : sw;
    const int* didx = second ? dl : dw;
    const int* cnt = second ? cl : cw;
    const float* beff = second ? bl : bw;
    const int b = second ? blockIdx.x - gh : blockIdx.x;

    const int lane = threadIdx.x & 63;
    const int gwave = (b * 256 + threadIdx.x) >> 6;
    const int nwave = (gh * 256) >> 6;
    const float bz0 = beff[2 * lane];
    const float bz1 = beff[2 * lane + 1];

    for (int base = gwave * 64; base < E; base += nwave * 64) {
        int e = base + lane;
        int su = (e < E) ? sidx[e] : 0;
        int dv = (e < E) ? didx[e] : 0;
        int cn = min(64, E - base);
        int cur = -1; float scl = 0.f, a0 = 0.f, a1 = 0.f, hv0 = 0.f, hv1 = 0.f;
        auto acc_one = [&](int j, uint uu) {
            int dd = __shfl(dv, j);
            if (dd != cur) {               // wave-uniform branch (shfl broadcast)
                if (cur >= 0) {
                    atomicAdd(&hacc[(size_t)cur * 128 + 2 * lane],     a0 * scl);
                    atomicAdd(&hacc[(size_t)cur * 128 + 2 * lane + 1], a1 * scl);
                }
                cur = dd; scl = 0.5f / fmaxf((float)cnt[dd], 1.f); a0 = 0.f; a1 = 0.f;
                uint vv = HV[(size_t)dd * 64 + lane];
                hv0 = bf2f(vv & 0xffffu); hv1 = bf2f(vv >> 16);
            }
            a0 += fmaxf(bf2f(uu & 0xffffu) + hv0 + bz0, 0.f);
            a1 += fmaxf(bf2f(uu >> 16)     + hv1 + bz1, 0.f);
        };
        if (cn == 64) {
            #pragma unroll
            for (int bb = 0; bb < 4; ++bb) {
                uint pre[16];
                #pragma unroll
                for (int k = 0; k < 16; ++k) {
                    int aa = __shfl(su, bb * 16 + k);
                    pre[k] = HU[(size_t)aa * 64 + lane];
                }
                #pragma unroll
                for (int k = 0; k < 16; ++k)
                    acc_one(bb * 16 + k, pre[k]);
            }
        } else {
            for (int j = 0; j < cn; ++j) {
                int aa = __shfl(su, j);
                acc_one(j, HU[(size_t)aa * 64 + lane]);
            }
        }
        if (cur >= 0) {
            atomicAdd(&hacc[(size_t)cur * 128 + 2 * lane],     a0 * scl);
            atomicAdd(&hacc[(size_t)cur * 128 + 2 * lane + 1], a1 * scl);
        }
    }
}

// ---------------- hacc -> bf16 h (+fh half) + fused column stats, re-zero hacc ----------------
__global__ __launch_bounds__(256) void finalize_hacc_stats(
    float2* __restrict__ hacc2, uint* __restrict__ h2, uint* __restrict__ fh2,
    int fhsel, int N,
    float* __restrict__ psA, float* __restrict__ pqA, int strideA, int offA,
    float* __restrict__ psB, float* __restrict__ pqB, int strideB, int offB) {
    const int cl = threadIdx.x & 63;
    const int sub = threadIdx.x >> 6;
    float s0=0,s1=0,q0=0,q1=0;
    for (int n = blockIdx.x * 4 + sub; n < N; n += gridDim.x * 4) {
        int i = n * 64 + cl;
        float2 v = hacc2[i];
        uint pk = (uint)f2bf(v.x) | ((uint)f2bf(v.y) << 16);
        h2[i] = pk;
        if (fhsel >= 0) fh2[(size_t)n * 128 + fhsel * 64 + cl] = pk;
        hacc2[i] = make_float2(0.f, 0.f);
        s0 += v.x; q0 += v.x * v.x;
        s1 += v.y; q1 += v.y * v.y;
    }
    __shared__ float red[4][64][4];
    red[sub][cl][0]=s0; red[sub][cl][1]=s1; red[sub][cl][2]=q0; red[sub][cl][3]=q1;
    __syncthreads();
    if (sub == 0) {
        #pragma unroll
        for (int k = 1; k < 4; ++k) {
            s0 += red[k][cl][0]; s1 += red[k][cl][1];
            q0 += red[k][cl][2]; q1 += red[k][cl][3];
        }
        psA[(size_t)blockIdx.x * strideA + offA + 2*cl]     = s0;
        psA[(size_t)blockIdx.x * strideA + offA + 2*cl + 1] = s1;
        pqA[(size_t)blockIdx.x * strideA + offA + 2*cl]     = q0;
        pqA[(size_t)blockIdx.x * strideA + offA + 2*cl + 1] = q1;
        if (psB) {
            psB[(size_t)blockIdx.x * strideB + offB + 2*cl]     = s0;
            psB[(size_t)blockIdx.x * strideB + offB + 2*cl + 1] = s1;
            pqB[(size_t)blockIdx.x * strideB + offB + 2*cl]     = q0;
            pqB[(size_t)blockIdx.x * strideB + offB + 2*cl + 1] = q1;
        }
    }
}

// ---------------- launch ----------------
extern "C" void kernel_launch(void* const* d_in, const int* in_sizes, int n_in,
                              void* d_out, int out_size, void* d_ws, size_t ws_size,
                              hipStream_t stream) {
    const float* win_f  = (const float*)d_in[0];
    const float* loss_f = (const float*)d_in[1];
    struct BP { const float *g, *b, *W, *bias; };
    auto bp = [&](int i) { return BP{ (const float*)d_in[i], (const float*)d_in[i+1],
                                      (const float*)d_in[i+2], (const float*)d_in[i+3] }; };
    BP wi = bp(2), li = bp(6), srcp = bp(10), dstp = bp(14), wl = bp(18), ll = bp(22), outp = bp(26);
    const int* win_src  = (const int*)d_in[30];
    const int* win_dst  = (const int*)d_in[31];
    const int* loss_src = (const int*)d_in[32];
    const int* loss_dst = (const int*)d_in[33];
    const int E = in_sizes[30];
    const int N = out_size / 128;
    (void)n_in;

    char* base = (char*)d_ws;
    size_t off_b = 0;
    auto alloc = [&](size_t bytes) {
        size_t cur = off_b;
        off_b += (bytes + 255) & ~(size_t)255;
        return (void*)(base + cur);
    };
    float*  hacc = (float*)alloc((size_t)N * 128 * 4);
    ushort* h    = (ushort*)alloc((size_t)N * 128 * 2);
    ushort* hu   = (ushort*)alloc((size_t)N * 128 * 2);
    ushort* hv   = (ushort*)alloc((size_t)N * 128 * 2);
    ushort* fh   = (ushort*)alloc((size_t)N * 256 * 2);
    ushort* HUw  = (ushort*)alloc((size_t)N * 128 * 2);
    ushort* HVw  = (ushort*)alloc((size_t)N * 128 * 2);
    ushort* HUl  = (ushort*)alloc((size_t)N * 128 * 2);
    ushort* HVl  = (ushort*)alloc((size_t)N * 128 * 2);
    int* cntw  = (int*)alloc((size_t)N * 4);
    int* cntl  = (int*)alloc((size_t)N * 4);
    int* offw  = (int*)alloc((size_t)(N + 1) * 4);
    int* offl  = (int*)alloc((size_t)(N + 1) * 4);
    int* curw  = (int*)alloc((size_t)N * 4);
    int* curl  = (int*)alloc((size_t)N * 4);
    int* permw = (int*)alloc((size_t)E * 4);
    int* ssrcw = (int*)alloc((size_t)E * 4);
    int* sdstw = (int*)alloc((size_t)E * 4);
    int* perml = (int*)alloc((size_t)E * 4);
    int* ssrcl = (int*)alloc((size_t)E * 4);
    int* sdstl = (int*)alloc((size_t)E * 4);
    float* psumW = (float*)alloc((size_t)NPART_MAX * 128 * 4);
    float* psqW  = (float*)alloc((size_t)NPART_MAX * 128 * 4);
    float* psumL = (float*)alloc((size_t)NPART_MAX * 128 * 4);
    float* psqL  = (float*)alloc((size_t)NPART_MAX * 128 * 4);
    float* psumN = (float*)alloc((size_t)512 * 128 * 4);
    float* psqN  = (float*)alloc((size_t)512 * 128 * 4);
    float* psum256 = (float*)alloc((size_t)512 * 256 * 4);
    float* psq256  = (float*)alloc((size_t)512 * 256 * 4);
    float* scal1 = (float*)alloc(256 * 4);
    float* shif1 = (float*)alloc(256 * 4);
    float* scal2 = (float*)alloc(256 * 4);
    float* shif2 = (float*)alloc(256 * 4);
    ushort* Wp1 = (ushort*)alloc((size_t)256 * 128 * 2);
    ushort* Wp2 = (ushort*)alloc((size_t)256 * 128 * 2);
    float* beff1 = (float*)alloc(128 * 4);
    float* beff2 = (float*)alloc(128 * 4);
    if (off_b > ws_size) return;   // workspace must fit

    const int gE64 = (E + 63) / 64;
    const int gN = (N + 127) / 128;
    const int NBF = 1024;   // fp32-stats blocks per etype
    const int NBG = 2048;   // gather/edge blocks per etype
    const int NBN = 512;    // finalize/stats blocks

    // phase 0: counting sort (both etypes)
    hipMemsetAsync(cntw, 0, (size_t)N * 4, stream);
    hipMemsetAsync(cntl, 0, (size_t)N * 4, stream);
    hipMemsetAsync(hacc, 0, (size_t)N * 128 * 4, stream);
    hist2<<<2048, 256, 0, stream>>>(win_dst, loss_dst, E, cntw, cntl);
    scan2<<<2, 256, 0, stream>>>(cntw, cntl, N, offw, curw, offl, curl);
    scatter2<<<2048, 256, 0, stream>>>(win_src, win_dst, loss_src, loss_dst, E,
                                       curw, curl, permw, ssrcw, sdstw, perml, ssrcl, sdstl);

    // initial edge blocks: linear fp32 stats + LDS-staged bf16-gather seg-GEMM
    stats_f32_2<<<2 * NBF, 256, 0, stream>>>(
        (const float4*)win_f, psumW, psqW,
        (const float4*)loss_f, psumL, psqL, E);
    reduce_stats2<<<256, 256, 0, stream>>>(
        psumW, psqW, NBF, 128, E, wi.g, wi.b, scal1, shif1,
        psumL, psqL, NBF, 128, E, li.g, li.b, scal2, shif2);
    pack_fold2<<<24, 256, 0, stream>>>(scal1, shif1, 128, wi.W, wi.bias, Wp1, beff1,
                                       scal2, shif2, 128, li.W, li.bias, Wp2, beff2);
    gemm_seg2<<<2 * gE64, 256, 0, stream>>>(
        win_f, permw, sdstw, cntw, Wp1, beff1, E,
        loss_f, perml, sdstl, cntl, Wp2, beff2, E, hacc);
    // finalize: h + fh(f-half) + h-stats (for iter0) + f-half stats (for final layer)
    finalize_hacc_stats<<<NBN, 256, 0, stream>>>(
        (float2*)hacc, (uint*)h, (uint*)fh, 0, N,
        psumN, psqN, 128, 0, psum256, psq256, 256, 0);

    for (int it = 0; it < 3; ++it) {
        reduce_stats<<<128, 256, 0, stream>>>(psumN, psqN, NBN, 128, N, srcp.g, srcp.b, scal1, shif1,
                                              dstp.g, dstp.b, scal2, shif2);
        pack_fold2<<<24, 256, 0, stream>>>(scal1, shif1, 128, srcp.W, srcp.bias, Wp1, beff1,
                                           scal2, shif2, 128, dstp.W, dstp.bias, Wp2, beff2);
        gemm_dual<<<2 * gN, 256, 0, stream>>>(h, Wp1, beff1, hu, Wp2, beff2, hv, N);

        gather_stats2<<<2 * NBG, 256, 0, stream>>>(
            (const uint2*)hu, (const uint2*)hv,
            ssrcw, sdstw, psumW, psqW, ssrcl, sdstl, psumL, psqL, E);
        reduce_stats2<<<256, 256, 0, stream>>>(
            psumW, psqW, NBG, 128, E, wl.g, wl.b, scal1, shif1,
            psumL, psqL, NBG, 128, E, ll.g, ll.b, scal2, shif2);
        pack_fold2<<<24, 256, 0, stream>>>(scal1, shif1, 128, wl.W, wl.bias, Wp1, beff1,
                                           scal2, shif2, 128, ll.W, ll.bias, Wp2, beff2);
        gemm_quad<<<4 * gN, 256, 0, stream>>>(hu, hv, Wp1, Wp2, HUw, HVw, HUl, HVl, N);
        edge_seg2<<<2 * NBG, 256, 0, stream>>>(
            (const uint*)HUw, (const uint*)HVw, ssrcw, sdstw, cntw, beff1,
            (const uint*)HUl, (const uint*)HVl, ssrcl, sdstl, cntl, beff2,
            hacc, E);
        if (it < 2) {
            finalize_hacc_stats<<<NBN, 256, 0, stream>>>(
                (float2*)hacc, (uint*)h, (uint*)fh, -1, N,
                psumN, psqN, 128, 0, nullptr, nullptr, 0, 0);
        } else {
            finalize_hacc_stats<<<NBN, 256, 0, stream>>>(
                (float2*)hacc, (uint*)h, (uint*)fh, 1, N,
                psum256, psq256, 256, 128, nullptr, nullptr, 0, 0);
        }
    }

    reduce_stats<<<256, 256, 0, stream>>>(psum256, psq256, NBN, 256, N, outp.g, outp.b, scal1, shif1,
                                          nullptr, nullptr, nullptr, nullptr);
    pack_fold_par<<<16, 256, 0, stream>>>(scal1, shif1, 256, outp.W, outp.bias, Wp1, beff1);
    gemm_final<<<gN, 256, 0, stream>>>(fh, Wp1, beff1, (float*)d_out, N);
}

// Round 20
// 712.766 us; speedup vs baseline: 1.0132x; 1.0132x over previous
//
#include <hip/hip_runtime.h>

#define NPART_MAX 2048

typedef __attribute__((ext_vector_type(8))) short short8;
typedef __attribute__((ext_vector_type(4))) float f32x4;

__device__ __forceinline__ float bf2f(uint u) {
    union { uint u; float f; } v; v.u = u << 16; return v.f;
}
__device__ __forceinline__ ushort f2bf(float f) {
    union { float f; uint u; } v; v.f = f;
    uint r = v.u + 0x7fffu + ((v.u >> 16) & 1u);
    return (ushort)(r >> 16);
}

// ---------------- phase 0: counting sort by dst (both etypes per launch) ----------------
__global__ __launch_bounds__(256) void hist2(const int* __restrict__ dw, const int* __restrict__ dl,
                                             int E, int* __restrict__ cw, int* __restrict__ cl) {
    const int half = gridDim.x >> 1;
    const bool second = (int)blockIdx.x >= half;
    const int* dst = second ? dl : dw;
    int* cnt = second ? cl : cw;
    const int b = second ? blockIdx.x - half : blockIdx.x;
    for (int e = b * 256 + threadIdx.x; e < E; e += half * 256)
        atomicAdd(&cnt[dst[e]], 1);
}

__global__ __launch_bounds__(256) void scan2(const int* __restrict__ cw, const int* __restrict__ cl,
                                             int n, int* offw, int* curw, int* offl, int* curl) {
    const int* cnt = blockIdx.x ? cl : cw;
    int* off = blockIdx.x ? offl : offw;
    int* cur = blockIdx.x ? curl : curw;
    __shared__ int warpsums[4];
    __shared__ int s_carry;
    if (threadIdx.x == 0) s_carry = 0;
    __syncthreads();
    for (int base = 0; base < n; base += 1024) {
        int i0 = base + threadIdx.x * 4;
        int v0 = (i0 + 0 < n) ? cnt[i0 + 0] : 0;
        int v1 = (i0 + 1 < n) ? cnt[i0 + 1] : 0;
        int v2 = (i0 + 2 < n) ? cnt[i0 + 2] : 0;
        int v3 = (i0 + 3 < n) ? cnt[i0 + 3] : 0;
        int tsum = v0 + v1 + v2 + v3;
        int lane = threadIdx.x & 63, w = threadIdx.x >> 6;
        int x = tsum;
        for (int d = 1; d < 64; d <<= 1) {
            int y = __shfl_up(x, d);
            if (lane >= d) x += y;
        }
        if (lane == 63) warpsums[w] = x;
        __syncthreads();
        int woff = 0;
        for (int k = 0; k < w; ++k) woff += warpsums[k];
        int excl = x - tsum + woff + s_carry;
        if (i0 + 0 < n) { off[i0 + 0] = excl; cur[i0 + 0] = excl; } excl += v0;
        if (i0 + 1 < n) { off[i0 + 1] = excl; cur[i0 + 1] = excl; } excl += v1;
        if (i0 + 2 < n) { off[i0 + 2] = excl; cur[i0 + 2] = excl; } excl += v2;
        if (i0 + 3 < n) { off[i0 + 3] = excl; cur[i0 + 3] = excl; } excl += v3;
        __syncthreads();
        if (threadIdx.x == 255) s_carry = excl;
        __syncthreads();
    }
    if (threadIdx.x == 0) off[n] = s_carry;
}

__global__ __launch_bounds__(256) void scatter2(
    const int* __restrict__ sw, const int* __restrict__ dw,
    const int* __restrict__ sl, const int* __restrict__ dl, int E,
    int* __restrict__ curw, int* __restrict__ curl,
    int* __restrict__ permw, int* __restrict__ ssrcw, int* __restrict__ sdstw,
    int* __restrict__ perml, int* __restrict__ ssrcl, int* __restrict__ sdstl) {
    const int half = gridDim.x >> 1;
    const bool second = (int)blockIdx.x >= half;
    const int* src = second ? sl : sw;
    const int* dst = second ? dl : dw;
    int* cursor = second ? curl : curw;
    int* perm = second ? perml : permw;
    int* ssrc = second ? ssrcl : ssrcw;
    int* sdst = second ? sdstl : sdstw;
    const int b = second ? blockIdx.x - half : blockIdx.x;
    for (int e = b * 256 + threadIdx.x; e < E; e += half * 256) {
        int d = dst[e];
        int p = atomicAdd(&cursor[d], 1);
        perm[p] = e;
        ssrc[p] = src[e];
        sdst[p] = d;
    }
}

// ---------------- dual linear fp32 col-stats ----------------
__device__ __forceinline__ void statsf_body(
    int b, int nb, const float4* __restrict__ x4, int M,
    float* __restrict__ psum, float* __restrict__ psq) {
    const int cg = threadIdx.x & 31;
    const int sub = threadIdx.x >> 5;
    float s0=0,s1=0,s2=0,s3=0,q0=0,q1=0,q2=0,q3=0;
    for (int r = b * 8 + sub; r < M; r += nb * 8) {
        float4 v = x4[(size_t)r * 32 + cg];
        s0 += v.x; q0 += v.x * v.x;
        s1 += v.y; q1 += v.y * v.y;
        s2 += v.z; q2 += v.z * v.z;
        s3 += v.w; q3 += v.w * v.w;
    }
    __shared__ float rs[256][4], rq[256][4];
    rs[threadIdx.x][0]=s0; rs[threadIdx.x][1]=s1; rs[threadIdx.x][2]=s2; rs[threadIdx.x][3]=s3;
    rq[threadIdx.x][0]=q0; rq[threadIdx.x][1]=q1; rq[threadIdx.x][2]=q2; rq[threadIdx.x][3]=q3;
    __syncthreads();
    if (sub == 0) {
        #pragma unroll
        for (int k = 1; k < 8; ++k) {
            s0 += rs[k*32+cg][0]; s1 += rs[k*32+cg][1];
            s2 += rs[k*32+cg][2]; s3 += rs[k*32+cg][3];
            q0 += rq[k*32+cg][0]; q1 += rq[k*32+cg][1];
            q2 += rq[k*32+cg][2]; q3 += rq[k*32+cg][3];
        }
        psum[b*128 + cg*4+0] = s0; psq[b*128 + cg*4+0] = q0;
        psum[b*128 + cg*4+1] = s1; psq[b*128 + cg*4+1] = q1;
        psum[b*128 + cg*4+2] = s2; psq[b*128 + cg*4+2] = q2;
        psum[b*128 + cg*4+3] = s3; psq[b*128 + cg*4+3] = q3;
    }
}

__global__ __launch_bounds__(256) void stats_f32_2(
    const float4* xa, float* psa, float* pqa,
    const float4* xb, float* psb, float* pqb, int M) {
    const int half = gridDim.x >> 1;
    const bool second = (int)blockIdx.x >= half;
    statsf_body(second ? blockIdx.x - half : blockIdx.x, half,
                second ? xb : xa, M, second ? psb : psa, second ? pqb : pqa);
}

// ---------------- dual gather stats: run-hoisted hv + batched hu prefetch ----------------
__global__ __launch_bounds__(256) void gather_stats2(
    const uint2* __restrict__ hu4, const uint2* __restrict__ hv4,
    const int* __restrict__ sw, const int* __restrict__ dw,
    float* __restrict__ psumW, float* __restrict__ psqW,
    const int* __restrict__ sl, const int* __restrict__ dl,
    float* __restrict__ psumL, float* __restrict__ psqL, int E) {
    const int gh = gridDim.x >> 1;
    const bool second = (int)blockIdx.x >= gh;
    const int* sidx = second ? sl : sw;
    const int* didx = second ? dl : dw;
    float* psum = second ? psumL : psumW;
    float* psq  = second ? psqL  : psqW;
    const int b = second ? blockIdx.x - gh : blockIdx.x;

    const int lane = threadIdx.x & 63;
    const int w = threadIdx.x >> 6;
    const int half = lane >> 5;
    const int cg = lane & 31;
    const int gwave = (b * 256 + threadIdx.x) >> 6;
    const int nwave = (gh * 256) >> 6;
    float s0=0,s1=0,s2=0,s3=0,q0=0,q1=0,q2=0,q3=0;
    for (int base = gwave * 64; base < E; base += nwave * 64) {
        int e = base + lane;
        int su = (e < E) ? sidx[e] : 0;
        int dv = (e < E) ? didx[e] : 0;
        int cnt = min(64, E - base);
        int curd = -1;
        float hv0=0,hv1=0,hv2=0,hv3=0;
        float rs0=0,rs1=0,rs2=0,rs3=0,rq0=0,rq1=0,rq2=0,rq3=0,rlen=0;
        auto flush = [&]() {
            if (curd >= 0) {
                s0 += rs0 + rlen*hv0; q0 += rq0 + 2.f*hv0*rs0 + rlen*hv0*hv0;
                s1 += rs1 + rlen*hv1; q1 += rq1 + 2.f*hv1*rs1 + rlen*hv1*hv1;
                s2 += rs2 + rlen*hv2; q2 += rq2 + 2.f*hv2*rs2 + rlen*hv2*hv2;
                s3 += rs3 + rlen*hv3; q3 += rq3 + 2.f*hv3*rs3 + rlen*hv3*hv3;
            }
        };
        auto acc_run = [&](int eidx, uint2 uu) {
            int dd = __shfl(dv, eidx);
            if (dd != curd) {
                flush();
                curd = dd;
                uint2 vv = hv4[(size_t)dd * 32 + cg];
                hv0 = bf2f(vv.x & 0xffffu); hv1 = bf2f(vv.x >> 16);
                hv2 = bf2f(vv.y & 0xffffu); hv3 = bf2f(vv.y >> 16);
                rs0=rs1=rs2=rs3=0; rq0=rq1=rq2=rq3=0; rlen=0;
            }
            float u0 = bf2f(uu.x & 0xffffu), u1 = bf2f(uu.x >> 16);
            float u2 = bf2f(uu.y & 0xffffu), u3 = bf2f(uu.y >> 16);
            rs0 += u0; rq0 += u0*u0;
            rs1 += u1; rq1 += u1*u1;
            rs2 += u2; rq2 += u2*u2;
            rs3 += u3; rq3 += u3*u3;
            rlen += 1.f;
        };
        if (cnt == 64) {
            #pragma unroll
            for (int bb = 0; bb < 4; ++bb) {
                uint2 pre[8];
                #pragma unroll
                for (int k = 0; k < 8; ++k) {
                    int a = __shfl(su, 2 * (bb * 8 + k) + half);
                    pre[k] = hu4[(size_t)a * 32 + cg];
                }
                #pragma unroll
                for (int k = 0; k < 8; ++k)
                    acc_run(2 * (bb * 8 + k) + half, pre[k]);
            }
        } else {
            for (int j = 0; j < 32; ++j) {
                int eidx = 2 * j + half;
                if (eidx < cnt) {
                    int a = __shfl(su, eidx);
                    acc_run(eidx, hu4[(size_t)a * 32 + cg]);
                }
            }
        }
        flush();
    }
    __shared__ float redS[8][32][4], redQ[8][32][4];
    const int ri = w * 2 + half;
    redS[ri][cg][0]=s0; redS[ri][cg][1]=s1; redS[ri][cg][2]=s2; redS[ri][cg][3]=s3;
    redQ[ri][cg][0]=q0; redQ[ri][cg][1]=q1; redQ[ri][cg][2]=q2; redQ[ri][cg][3]=q3;
    __syncthreads();
    if (threadIdx.x < 128) {
        int c = threadIdx.x;
        int cgg = c >> 2, k = c & 3;
        float s = 0.f, q = 0.f;
        #pragma unroll
        for (int i = 0; i < 8; ++i) { s += redS[i][cgg][k]; q += redQ[i][cgg][k]; }
        psum[(size_t)b * 128 + c] = s;
        psq [(size_t)b * 128 + c] = q;
    }
}

// ---------------- per-column reduce of partials -> scale/shift ----------------
__device__ __forceinline__ void reduce_body(
    int c, const float* __restrict__ psum, const float* __restrict__ psq,
    int nblk, int C, int M,
    const float* __restrict__ g1, const float* __restrict__ b1,
    float* __restrict__ scale1, float* __restrict__ shift1,
    const float* g2, const float* b2, float* scale2, float* shift2) {
    double s = 0.0, q = 0.0;
    for (int i = threadIdx.x; i < nblk; i += 256) {
        s += (double)psum[(size_t)i * C + c];
        q += (double)psq [(size_t)i * C + c];
    }
    __shared__ double ss[256], qs[256];
    ss[threadIdx.x] = s; qs[threadIdx.x] = q;
    __syncthreads();
    for (int d = 128; d > 0; d >>= 1) {
        if (threadIdx.x < d) {
            ss[threadIdx.x] += ss[threadIdx.x + d];
            qs[threadIdx.x] += qs[threadIdx.x + d];
        }
        __syncthreads();
    }
    if (threadIdx.x == 0) {
        double m = ss[0] / (double)M;
        double v = qs[0] / (double)M - m * m;
        if (v < 0.0) v = 0.0;
        double rs = 1.0 / sqrt(v + 1e-5);
        float mf = (float)m;
        float sc1 = (float)(rs * (double)g1[c]);
        scale1[c] = sc1;
        shift1[c] = b1[c] - mf * sc1;
        if (g2) {
            float sc2 = (float)(rs * (double)g2[c]);
            scale2[c] = sc2;
            shift2[c] = b2[c] - mf * sc2;
        }
    }
}

__global__ __launch_bounds__(256) void reduce_stats(
    const float* psum, const float* psq, int nblk, int C, int M,
    const float* g1, const float* b1, float* scale1, float* shift1,
    const float* g2, const float* b2, float* scale2, float* shift2) {
    reduce_body(blockIdx.x, psum, psq, nblk, C, M, g1, b1, scale1, shift1, g2, b2, scale2, shift2);
}

__global__ __launch_bounds__(256) void reduce_stats2(
    const float* psumA, const float* psqA, int nblkA, int CA, int MA,
    const float* gA, const float* bA, float* scaleA, float* shiftA,
    const float* psumB, const float* psqB, int nblkB, int CB, int MB,
    const float* gB, const float* bB, float* scaleB, float* shiftB) {
    if ((int)blockIdx.x < CA)
        reduce_body(blockIdx.x, psumA, psqA, nblkA, CA, MA, gA, bA, scaleA, shiftA,
                    nullptr, nullptr, nullptr, nullptr);
    else
        reduce_body(blockIdx.x - CA, psumB, psqB, nblkB, CB, MB, gB, bB, scaleB, shiftB,
                    nullptr, nullptr, nullptr, nullptr);
}

// ---------------- parallel BN fold + MFMA-fragment pack ----------------
__device__ __forceinline__ void fold_body(
    int b, const float* __restrict__ scale, const float* __restrict__ shift, int C,
    const float* __restrict__ W, const float* __restrict__ bias,
    ushort* __restrict__ Wp, float* __restrict__ beff) {
    const int KT = C / 32;
    __shared__ float slab[32 * 128];
    if (b < KT) {
        const int kt = b;
        for (int i = threadIdx.x; i < 32 * 128; i += 256) {
            int kr = i >> 7, d = i & 127;
            int c = kt * 32 + kr;
            slab[i] = W[(size_t)c * 128 + d] * scale[c];
        }
        __syncthreads();
        #pragma unroll
        for (int t0 = 0; t0 < 512; t0 += 256) {
            int t = t0 + threadIdx.x;
            int lane = t & 63, dt = t >> 6;
            int d = dt * 16 + (lane & 15);
            int kb = (lane >> 4) * 8;
            uint4 o;
            o.x = (uint)f2bf(slab[(kb+0)*128 + d]) | ((uint)f2bf(slab[(kb+1)*128 + d]) << 16);
            o.y = (uint)f2bf(slab[(kb+2)*128 + d]) | ((uint)f2bf(slab[(kb+3)*128 + d]) << 16);
            o.z = (uint)f2bf(slab[(kb+4)*128 + d]) | ((uint)f2bf(slab[(kb+5)*128 + d]) << 16);
            o.w = (uint)f2bf(slab[(kb+6)*128 + d]) | ((uint)f2bf(slab[(kb+7)*128 + d]) << 16);
            *(uint4*)(Wp + (size_t)((dt * KT + kt) * 64 + lane) * 8) = o;
        }
    } else {
        const int bb = b - KT;
        const int dl = threadIdx.x & 15, ci = threadIdx.x >> 4;
        const int d = bb * 16 + dl;
        float a = 0.f;
        for (int c = ci; c < C; c += 16)
            a += shift[c] * W[(size_t)c * 128 + d];
        float* red = slab;
        red[threadIdx.x] = a;
        __syncthreads();
        if (ci == 0) {
            #pragma unroll
            for (int k = 1; k < 16; ++k) a += red[k * 16 + dl];
            beff[d] = bias[d] + a;
        }
    }
}

__global__ __launch_bounds__(256) void pack_fold_par(
    const float* scale, const float* shift, int C,
    const float* W, const float* bias, ushort* Wp, float* beff) {
    fold_body(blockIdx.x, scale, shift, C, W, bias, Wp, beff);
}

__global__ __launch_bounds__(256) void pack_fold2(
    const float* scaleA, const float* shiftA, int CA, const float* WA, const float* biasA,
    ushort* WpA, float* beffA,
    const float* scaleB, const float* shiftB, int CB, const float* WB, const float* biasB,
    ushort* WpB, float* beffB) {
    const int nA = CA / 32 + 8;
    const bool second = (int)blockIdx.x >= nA;
    fold_body(second ? blockIdx.x - nA : blockIdx.x,
              second ? scaleB : scaleA, second ? shiftB : shiftA, second ? CB : CA,
              second ? WB : WA, second ? biasB : biasA,
              second ? WpB : WpA, second ? beffB : beffA);
}

// ---------------- plain MFMA GEMM. MODE: 0=bf16 bias+relu, 1=f32 bias+relu, 2=bf16 plain ----------------
template<int KT, int MODE>
__device__ __forceinline__ void gemm_body(
    int b, const ushort* __restrict__ X,
    const ushort* __restrict__ Wp, const float* __restrict__ beff,
    ushort* __restrict__ Yb, float* __restrict__ Yf, int M) {
    constexpr int K = KT * 32;
    const int lane = threadIdx.x & 63;
    const int w = threadIdx.x >> 6;
    const int r0 = b * 128 + w * 32;
    const int rlo = lane & 15, khi = lane >> 4;

    f32x4 acc[2][8];
    #pragma unroll
    for (int rt = 0; rt < 2; ++rt)
        #pragma unroll
        for (int dt = 0; dt < 8; ++dt)
            acc[rt][dt] = (f32x4){0.f, 0.f, 0.f, 0.f};

    int row[2], idx[2];
    bool ok[2];
    #pragma unroll
    for (int rt = 0; rt < 2; ++rt) {
        row[rt] = r0 + rt * 16 + rlo;
        ok[rt] = row[rt] < M;
        idx[rt] = ok[rt] ? row[rt] : 0;
    }

    for (int kt = 0; kt < KT; ++kt) {
        short8 wf[8];
        #pragma unroll
        for (int dt = 0; dt < 8; ++dt)
            wf[dt] = *(const short8*)(Wp + (size_t)((dt * KT + kt) * 64 + lane) * 8);
        #pragma unroll
        for (int rt = 0; rt < 2; ++rt) {
            short8 bv = *(const short8*)(X + (size_t)idx[rt] * K + kt * 32 + khi * 8);
            #pragma unroll
            for (int dt = 0; dt < 8; ++dt)
                acc[rt][dt] = __builtin_amdgcn_mfma_f32_16x16x32_bf16(wf[dt], bv, acc[rt][dt], 0, 0, 0);
        }
    }

    #pragma unroll
    for (int rt = 0; rt < 2; ++rt) {
        if (!ok[rt]) continue;
        #pragma unroll
        for (int dt = 0; dt < 8; ++dt) {
            float v0, v1, v2, v3;
            if constexpr (MODE == 2) {
                v0 = acc[rt][dt][0]; v1 = acc[rt][dt][1];
                v2 = acc[rt][dt][2]; v3 = acc[rt][dt][3];
            } else {
                const float4 bz = *(const float4*)(beff + dt * 16 + khi * 4);
                v0 = fmaxf(acc[rt][dt][0] + bz.x, 0.f);
                v1 = fmaxf(acc[rt][dt][1] + bz.y, 0.f);
                v2 = fmaxf(acc[rt][dt][2] + bz.z, 0.f);
                v3 = fmaxf(acc[rt][dt][3] + bz.w, 0.f);
            }
            if constexpr (MODE == 1) {
                *(float4*)(Yf + (size_t)row[rt] * 128 + dt * 16 + khi * 4) = make_float4(v0, v1, v2, v3);
            } else {
                uint2 pk;
                pk.x = (uint)f2bf(v0) | ((uint)f2bf(v1) << 16);
                pk.y = (uint)f2bf(v2) | ((uint)f2bf(v3) << 16);
                *(uint2*)(Yb + (size_t)row[rt] * 128 + dt * 16 + khi * 4) = pk;
            }
        }
    }
}

__global__ __launch_bounds__(256) void gemm_final(
    const ushort* X, const ushort* Wp, const float* beff, float* Yf, int M) {
    gemm_body<8, 1>(blockIdx.x, X, Wp, beff, nullptr, Yf, M);
}

__global__ __launch_bounds__(256) void gemm_dual(
    const ushort* X,
    const ushort* Wp1, const float* beff1, ushort* Y1,
    const ushort* Wp2, const float* beff2, ushort* Y2, int M) {
    const int half = gridDim.x >> 1;
    const bool second = (int)blockIdx.x >= half;
    gemm_body<4, 0>(second ? blockIdx.x - half : blockIdx.x, X,
                    second ? Wp2 : Wp1, second ? beff2 : beff1,
                    second ? Y2 : Y1, nullptr, M);
}

// 4 node GEMMs (no bias/relu): hu@Wp1->HUw, hv@Wp1->HVw, hu@Wp2->HUl, hv@Wp2->HVl
__global__ __launch_bounds__(256) void gemm_quad(
    const ushort* hu, const ushort* hv,
    const ushort* Wp1, const ushort* Wp2,
    ushort* HUw, ushort* HVw, ushort* HUl, ushort* HVl, int M) {
    const int gq = gridDim.x >> 2;
    const int q = blockIdx.x / gq;
    const int b = blockIdx.x - q * gq;
    const ushort* X = (q & 1) ? hv : hu;
    const ushort* Wp = (q >= 2) ? Wp2 : Wp1;
    ushort* Y = (q == 0) ? HUw : (q == 1) ? HVw : (q == 2) ? HUl : HVl;
    gemm_body<4, 2>(b, X, Wp, nullptr, Y, nullptr, M);
}

// ---------------- seg-GEMM: 64-row blocks, LDS-staged fp32 gather, fused segmented mean ----------------
// Stage: block cooperatively gathers 64 rows (512B each) into LDS with 8 independent
// float4 loads/thread (high MLP, low VGPR). MFMA reads fragments from LDS. The same LDS
// is then reused (after barrier) as the bf16 output tile for the segmented-mean epilogue.
__device__ __forceinline__ void gemm_seg_body(
    int b, const float* __restrict__ XF, const int* __restrict__ perm,
    const int* __restrict__ sdst, const int* __restrict__ cnt,
    const ushort* __restrict__ Wp, const float* __restrict__ beff,
    float* __restrict__ hacc, int M) {
    __shared__ float xs[64 * 132];          // 33792 B staging; reused as ushort tile later
    __shared__ int   s_node[64];
    __shared__ float s_scale[64];
    __shared__ int   s_pidx[64];
    const int tid = threadIdx.x;
    const int lane = tid & 63;
    const int w = tid >> 6;
    const int rb = b * 64;
    const int rlo = lane & 15, khi = lane >> 4;

    if (tid < 64) {
        int r = rb + tid;
        bool in = (r < M);
        int nd = in ? sdst[r] : -1;
        s_node[tid] = nd;
        s_scale[tid] = (nd >= 0) ? 0.5f / fmaxf((float)cnt[nd], 1.f) : 0.f;
        s_pidx[tid] = in ? perm[r] : 0;
    }
    __syncthreads();

    // cooperative gather: 64 rows x 32 chunks of 16B = 2048 chunks; 8 per thread
    {
        float4 v[8];
        int rowi[8], coli[8];
        #pragma unroll
        for (int i = 0; i < 8; ++i) {
            int c = tid + 256 * i;
            rowi[i] = c >> 5;
            coli[i] = c & 31;
            v[i] = *(const float4*)(XF + (size_t)s_pidx[rowi[i]] * 128 + coli[i] * 4);
        }
        #pragma unroll
        for (int i = 0; i < 8; ++i)
            *(float4*)&xs[rowi[i] * 132 + coli[i] * 4] = v[i];
    }
    __syncthreads();

    f32x4 acc[8];
    #pragma unroll
    for (int dt = 0; dt < 8; ++dt)
        acc[dt] = (f32x4){0.f, 0.f, 0.f, 0.f};

    const int row = rb + w * 16 + rlo;
    const bool ok = row < M;
    const int rl = w * 16 + rlo;

    #pragma unroll
    for (int kt = 0; kt < 4; ++kt) {
        const float* p = &xs[rl * 132 + kt * 32 + khi * 8];
        float4 xa = *(const float4*)p;
        float4 xb = *(const float4*)(p + 4);
        short8 bv;
        bv[0] = (short)f2bf(xa.x); bv[1] = (short)f2bf(xa.y);
        bv[2] = (short)f2bf(xa.z); bv[3] = (short)f2bf(xa.w);
        bv[4] = (short)f2bf(xb.x); bv[5] = (short)f2bf(xb.y);
        bv[6] = (short)f2bf(xb.z); bv[7] = (short)f2bf(xb.w);
        #pragma unroll
        for (int dt = 0; dt < 8; ++dt) {
            short8 wf = *(const short8*)(Wp + (size_t)((dt * 4 + kt) * 64 + lane) * 8);
            acc[dt] = __builtin_amdgcn_mfma_f32_16x16x32_bf16(wf, bv, acc[dt], 0, 0, 0);
        }
    }
    __syncthreads();   // all LDS reads of xs done before tile overwrite

    ushort* tile = (ushort*)xs;            // reuse staging LDS as 64x132 ushort tile
    #pragma unroll
    for (int dt = 0; dt < 8; ++dt) {
        const float4 bz = *(const float4*)(beff + dt * 16 + khi * 4);
        float v0 = 0.f, v1 = 0.f, v2 = 0.f, v3 = 0.f;
        if (ok) {
            v0 = fmaxf(acc[dt][0] + bz.x, 0.f);
            v1 = fmaxf(acc[dt][1] + bz.y, 0.f);
            v2 = fmaxf(acc[dt][2] + bz.z, 0.f);
            v3 = fmaxf(acc[dt][3] + bz.w, 0.f);
        }
        uint2 pk;
        pk.x = (uint)f2bf(v0) | ((uint)f2bf(v1) << 16);
        pk.y = (uint)f2bf(v2) | ((uint)f2bf(v3) << 16);
        *(uint2*)&tile[rl * 132 + dt * 16 + khi * 4] = pk;
    }
    __syncthreads();

    // epilogue: 4 segments x 16 rows, uint col-pairs (64 per block)
    const int cp = tid & 63;
    const int rs = (tid >> 6) * 16;
    int cur = s_node[rs];
    float scl = s_scale[rs];
    float su0 = 0.f, su1 = 0.f;
    for (int r = rs; r < rs + 16; ++r) {
        int nd = s_node[r];
        if (nd != cur) {
            if (cur >= 0) {
                atomicAdd(&hacc[(size_t)cur * 128 + 2*cp],     su0 * scl);
                atomicAdd(&hacc[(size_t)cur * 128 + 2*cp + 1], su1 * scl);
            }
            cur = nd; scl = s_scale[r]; su0 = 0.f; su1 = 0.f;
        }
        uint u = *(const uint*)&tile[r * 132 + 2*cp];
        su0 += bf2f(u & 0xffffu);
        su1 += bf2f(u >> 16);
    }
    if (cur >= 0) {
        atomicAdd(&hacc[(size_t)cur * 128 + 2*cp],     su0 * scl);
        atomicAdd(&hacc[(size_t)cur * 128 + 2*cp + 1], su1 * scl);
    }
}

__global__ __launch_bounds__(256) void gemm_seg2(
    const float* XA, const int* permA, const int* sdstA, const int* cntA,
    const ushort* WpA, const float* beffA, int MA,
    const float* XB, const int* permB, const int* sdstB, const int* cntB,
    const ushort* WpB, const float* beffB, int MB,
    float* hacc) {
    const int half = gridDim.x >> 1;
    const bool second = (int)blockIdx.x >= half;
    gemm_seg_body(second ? blockIdx.x - half : blockIdx.x,
                  second ? XB : XA, second ? permB : permA,
                  second ? sdstB : sdstA, second ? cntB : cntA,
                  second ? WpB : WpA, second ? beffB : beffA,
                  hacc, second ? MB : MA);
}

// ---------------- edge gather-add-relu + segmented mean (dual, run-hoisted HV, batched HU prefetch) ----------------
__global__ __launch_bounds__(256) void edge_seg2(
    const uint* __restrict__ HUw, const uint* __restrict__ HVw,
    const int* __restrict__ sw, const int* __restrict__ dw,
    const int* __restrict__ cw, const float* __restrict__ bw,
    const uint* __restrict__ HUl, const uint* __restrict__ HVl,
    const int* __restrict__ sl, const int* __restrict__ dl,
    const int* __restrict__ cl, const float* __restrict__ bl,
    float* __restrict__ hacc, int E) {
    const int gh = gridDim.x >> 1;
    const bool second = (int)blockIdx.x >= gh;
    const uint* HU = second ? HUl : HUw;
    const uint* HV = second ? HVl : HVw;
    const int* sidx = second ? sl : sw;
    const int* didx = second ? dl : dw;
    const int* cnt = second ? cl : cw;
    const float* beff = second ? bl : bw;
    const int b = second ? blockIdx.x - gh : blockIdx.x;

    const int lane = threadIdx.x & 63;
    const int gwave = (b * 256 + threadIdx.x) >> 6;
    const int nwave = (gh * 256) >> 6;
    const float bz0 = beff[2 * lane];
    const float bz1 = beff[2 * lane + 1];

    for (int base = gwave * 64; base < E; base += nwave * 64) {
        int e = base + lane;
        int su = (e < E) ? sidx[e] : 0;
        int dv = (e < E) ? didx[e] : 0;
        int cn = min(64, E - base);
        int cur = -1; float scl = 0.f, a0 = 0.f, a1 = 0.f, hv0 = 0.f, hv1 = 0.f;
        auto acc_one = [&](int j, uint uu) {
            int dd = __shfl(dv, j);
            if (dd != cur) {               // wave-uniform branch (shfl broadcast)
                if (cur >= 0) {
                    atomicAdd(&hacc[(size_t)cur * 128 + 2 * lane],     a0 * scl);
                    atomicAdd(&hacc[(size_t)cur * 128 + 2 * lane + 1], a1 * scl);
                }
                cur = dd; scl = 0.5f / fmaxf((float)cnt[dd], 1.f); a0 = 0.f; a1 = 0.f;
                uint vv = HV[(size_t)dd * 64 + lane];
                hv0 = bf2f(vv & 0xffffu); hv1 = bf2f(vv >> 16);
            }
            a0 += fmaxf(bf2f(uu & 0xffffu) + hv0 + bz0, 0.f);
            a1 += fmaxf(bf2f(uu >> 16)     + hv1 + bz1, 0.f);
        };
        if (cn == 64) {
            #pragma unroll
            for (int bb = 0; bb < 4; ++bb) {
                uint pre[16];
                #pragma unroll
                for (int k = 0; k < 16; ++k) {
                    int aa = __shfl(su, bb * 16 + k);
                    pre[k] = HU[(size_t)aa * 64 + lane];
                }
                #pragma unroll
                for (int k = 0; k < 16; ++k)
                    acc_one(bb * 16 + k, pre[k]);
            }
        } else {
            for (int j = 0; j < cn; ++j) {
                int aa = __shfl(su, j);
                acc_one(j, HU[(size_t)aa * 64 + lane]);
            }
        }
        if (cur >= 0) {
            atomicAdd(&hacc[(size_t)cur * 128 + 2 * lane],     a0 * scl);
            atomicAdd(&hacc[(size_t)cur * 128 + 2 * lane + 1], a1 * scl);
        }
    }
}

// ---------------- hacc -> bf16 h (+fh half) + fused column stats, re-zero hacc ----------------
__global__ __launch_bounds__(256) void finalize_hacc_stats(
    float2* __restrict__ hacc2, uint* __restrict__ h2, uint* __restrict__ fh2,
    int fhsel, int N,
    float* __restrict__ psA, float* __restrict__ pqA, int strideA, int offA,
    float* __restrict__ psB, float* __restrict__ pqB, int strideB, int offB) {
    const int cl = threadIdx.x & 63;
    const int sub = threadIdx.x >> 6;
    float s0=0,s1=0,q0=0,q1=0;
    for (int n = blockIdx.x * 4 + sub; n < N; n += gridDim.x * 4) {
        int i = n * 64 + cl;
        float2 v = hacc2[i];
        uint pk = (uint)f2bf(v.x) | ((uint)f2bf(v.y) << 16);
        h2[i] = pk;
        if (fhsel >= 0) fh2[(size_t)n * 128 + fhsel * 64 + cl] = pk;
        hacc2[i] = make_float2(0.f, 0.f);
        s0 += v.x; q0 += v.x * v.x;
        s1 += v.y; q1 += v.y * v.y;
    }
    __shared__ float red[4][64][4];
    red[sub][cl][0]=s0; red[sub][cl][1]=s1; red[sub][cl][2]=q0; red[sub][cl][3]=q1;
    __syncthreads();
    if (sub == 0) {
        #pragma unroll
        for (int k = 1; k < 4; ++k) {
            s0 += red[k][cl][0]; s1 += red[k][cl][1];
            q0 += red[k][cl][2]; q1 += red[k][cl][3];
        }
        psA[(size_t)blockIdx.x * strideA + offA + 2*cl]     = s0;
        psA[(size_t)blockIdx.x * strideA + offA + 2*cl + 1] = s1;
        pqA[(size_t)blockIdx.x * strideA + offA + 2*cl]     = q0;
        pqA[(size_t)blockIdx.x * strideA + offA + 2*cl + 1] = q1;
        if (psB) {
            psB[(size_t)blockIdx.x * strideB + offB + 2*cl]     = s0;
            psB[(size_t)blockIdx.x * strideB + offB + 2*cl + 1] = s1;
            pqB[(size_t)blockIdx.x * strideB + offB + 2*cl]     = q0;
            pqB[(size_t)blockIdx.x * strideB + offB + 2*cl + 1] = q1;
        }
    }
}

// ---------------- launch ----------------
extern "C" void kernel_launch(void* const* d_in, const int* in_sizes, int n_in,
                              void* d_out, int out_size, void* d_ws, size_t ws_size,
                              hipStream_t stream) {
    const float* win_f  = (const float*)d_in[0];
    const float* loss_f = (const float*)d_in[1];
    struct BP { const float *g, *b, *W, *bias; };
    auto bp = [&](int i) { return BP{ (const float*)d_in[i], (const float*)d_in[i+1],
                                      (const float*)d_in[i+2], (const float*)d_in[i+3] }; };
    BP wi = bp(2), li = bp(6), srcp = bp(10), dstp = bp(14), wl = bp(18), ll = bp(22), outp = bp(26);
    const int* win_src  = (const int*)d_in[30];
    const int* win_dst  = (const int*)d_in[31];
    const int* loss_src = (const int*)d_in[32];
    const int* loss_dst = (const int*)d_in[33];
    const int E = in_sizes[30];
    const int N = out_size / 128;
    (void)n_in;

    char* base = (char*)d_ws;
    size_t off_b = 0;
    auto alloc = [&](size_t bytes) {
        size_t cur = off_b;
        off_b += (bytes + 255) & ~(size_t)255;
        return (void*)(base + cur);
    };
    float*  hacc = (float*)alloc((size_t)N * 128 * 4);
    ushort* h    = (ushort*)alloc((size_t)N * 128 * 2);
    ushort* hu   = (ushort*)alloc((size_t)N * 128 * 2);
    ushort* hv   = (ushort*)alloc((size_t)N * 128 * 2);
    ushort* fh   = (ushort*)alloc((size_t)N * 256 * 2);
    ushort* HUw  = (ushort*)alloc((size_t)N * 128 * 2);
    ushort* HVw  = (ushort*)alloc((size_t)N * 128 * 2);
    ushort* HUl  = (ushort*)alloc((size_t)N * 128 * 2);
    ushort* HVl  = (ushort*)alloc((size_t)N * 128 * 2);
    int* cntw  = (int*)alloc((size_t)N * 4);
    int* cntl  = (int*)alloc((size_t)N * 4);
    int* offw  = (int*)alloc((size_t)(N + 1) * 4);
    int* offl  = (int*)alloc((size_t)(N + 1) * 4);
    int* curw  = (int*)alloc((size_t)N * 4);
    int* curl  = (int*)alloc((size_t)N * 4);
    int* permw = (int*)alloc((size_t)E * 4);
    int* ssrcw = (int*)alloc((size_t)E * 4);
    int* sdstw = (int*)alloc((size_t)E * 4);
    int* perml = (int*)alloc((size_t)E * 4);
    int* ssrcl = (int*)alloc((size_t)E * 4);
    int* sdstl = (int*)alloc((size_t)E * 4);
    float* psumW = (float*)alloc((size_t)NPART_MAX * 128 * 4);
    float* psqW  = (float*)alloc((size_t)NPART_MAX * 128 * 4);
    float* psumL = (float*)alloc((size_t)NPART_MAX * 128 * 4);
    float* psqL  = (float*)alloc((size_t)NPART_MAX * 128 * 4);
    float* psumN = (float*)alloc((size_t)512 * 128 * 4);
    float* psqN  = (float*)alloc((size_t)512 * 128 * 4);
    float* psum256 = (float*)alloc((size_t)512 * 256 * 4);
    float* psq256  = (float*)alloc((size_t)512 * 256 * 4);
    float* scal1 = (float*)alloc(256 * 4);
    float* shif1 = (float*)alloc(256 * 4);
    float* scal2 = (float*)alloc(256 * 4);
    float* shif2 = (float*)alloc(256 * 4);
    ushort* Wp1 = (ushort*)alloc((size_t)256 * 128 * 2);
    ushort* Wp2 = (ushort*)alloc((size_t)256 * 128 * 2);
    float* beff1 = (float*)alloc(128 * 4);
    float* beff2 = (float*)alloc(128 * 4);
    if (off_b > ws_size) return;   // workspace must fit

    const int gE64 = (E + 63) / 64;
    const int gN = (N + 127) / 128;
    const int NBF = 1024;   // fp32-stats blocks per etype
    const int NBG = 2048;   // gather/edge blocks per etype
    const int NBN = 512;    // finalize/stats blocks

    // phase 0: counting sort (both etypes)
    hipMemsetAsync(cntw, 0, (size_t)N * 4, stream);
    hipMemsetAsync(cntl, 0, (size_t)N * 4, stream);
    hipMemsetAsync(hacc, 0, (size_t)N * 128 * 4, stream);
    hist2<<<2048, 256, 0, stream>>>(win_dst, loss_dst, E, cntw, cntl);
    scan2<<<2, 256, 0, stream>>>(cntw, cntl, N, offw, curw, offl, curl);
    scatter2<<<2048, 256, 0, stream>>>(win_src, win_dst, loss_src, loss_dst, E,
                                       curw, curl, permw, ssrcw, sdstw, perml, ssrcl, sdstl);

    // initial edge blocks: linear fp32 stats + LDS-staged fp32-gather seg-GEMM
    stats_f32_2<<<2 * NBF, 256, 0, stream>>>(
        (const float4*)win_f, psumW, psqW,
        (const float4*)loss_f, psumL, psqL, E);
    reduce_stats2<<<256, 256, 0, stream>>>(
        psumW, psqW, NBF, 128, E, wi.g, wi.b, scal1, shif1,
        psumL, psqL, NBF, 128, E, li.g, li.b, scal2, shif2);
    pack_fold2<<<24, 256, 0, stream>>>(scal1, shif1, 128, wi.W, wi.bias, Wp1, beff1,
                                       scal2, shif2, 128, li.W, li.bias, Wp2, beff2);
    gemm_seg2<<<2 * gE64, 256, 0, stream>>>(
        win_f, permw, sdstw, cntw, Wp1, beff1, E,
        loss_f, perml, sdstl, cntl, Wp2, beff2, E, hacc);
    // finalize: h + fh(f-half) + h-stats (for iter0) + f-half stats (for final layer)
    finalize_hacc_stats<<<NBN, 256, 0, stream>>>(
        (float2*)hacc, (uint*)h, (uint*)fh, 0, N,
        psumN, psqN, 128, 0, psum256, psq256, 256, 0);

    for (int it = 0; it < 3; ++it) {
        reduce_stats<<<128, 256, 0, stream>>>(psumN, psqN, NBN, 128, N, srcp.g, srcp.b, scal1, shif1,
                                              dstp.g, dstp.b, scal2, shif2);
        pack_fold2<<<24, 256, 0, stream>>>(scal1, shif1, 128, srcp.W, srcp.bias, Wp1, beff1,
                                           scal2, shif2, 128, dstp.W, dstp.bias, Wp2, beff2);
        gemm_dual<<<2 * gN, 256, 0, stream>>>(h, Wp1, beff1, hu, Wp2, beff2, hv, N);

        gather_stats2<<<2 * NBG, 256, 0, stream>>>(
            (const uint2*)hu, (const uint2*)hv,
            ssrcw, sdstw, psumW, psqW, ssrcl, sdstl, psumL, psqL, E);
        reduce_stats2<<<256, 256, 0, stream>>>(
            psumW, psqW, NBG, 128, E, wl.g, wl.b, scal1, shif1,
            psumL, psqL, NBG, 128, E, ll.g, ll.b, scal2, shif2);
        pack_fold2<<<24, 256, 0, stream>>>(scal1, shif1, 128, wl.W, wl.bias, Wp1, beff1,
                                           scal2, shif2, 128, ll.W, ll.bias, Wp2, beff2);
        gemm_quad<<<4 * gN, 256, 0, stream>>>(hu, hv, Wp1, Wp2, HUw, HVw, HUl, HVl, N);
        edge_seg2<<<2 * NBG, 256, 0, stream>>>(
            (const uint*)HUw, (const uint*)HVw, ssrcw, sdstw, cntw, beff1,
            (const uint*)HUl, (const uint*)HVl, ssrcl, sdstl, cntl, beff2,
            hacc, E);
        if (it < 2) {
            finalize_hacc_stats<<<NBN, 256, 0, stream>>>(
                (float2*)hacc, (uint*)h, (uint*)fh, -1, N,
                psumN, psqN, 128, 0, nullptr, nullptr, 0, 0);
        } else {
            finalize_hacc_stats<<<NBN, 256, 0, stream>>>(
                (float2*)hacc, (uint*)h, (uint*)fh, 1, N,
                psum256, psq256, 256, 128, nullptr, nullptr, 0, 0);
        }
    }

    reduce_stats<<<256, 256, 0, stream>>>(psum256, psq256, NBN, 256, N, outp.g, outp.b, scal1, shif1,
                                          nullptr, nullptr, nullptr, nullptr);
    pack_fold_par<<<16, 256, 0, stream>>>(scal1, shif1, 256, outp.W, outp.bias, Wp1, beff1);
    gemm_final<<<gN, 256, 0, stream>>>(fh, Wp1, beff1, (float*)d_out, N);
}